// Round 5
// baseline (712.661 us; speedup 1.0000x reference)
//
#include <hip/hip_runtime.h>
#include <stdint.h>

#define BB 8
#define LL 2048
#define EE 512
#define HH 8
#define DD 64

typedef __attribute__((ext_vector_type(8))) short short8;
typedef __attribute__((ext_vector_type(4))) float f32x4;
typedef __attribute__((ext_vector_type(16))) float f32x16;
typedef __attribute__((ext_vector_type(2))) unsigned int u32x2v;

// q pre-scale: log2(e)/sqrt(512), so attention uses bare exp2
#define QSCALE 0.06376435773361453f

// pack two f32 -> two bf16 (round-half-up) in one dword: low=a, high=b
__device__ __forceinline__ uint32_t pk2bf(float a, float b) {
    union { float f; uint32_t u; } va, vb; va.f = a; vb.f = b;
    return __builtin_amdgcn_perm(vb.u + 0x8000u, va.u + 0x8000u, 0x07060302u);
}

// build a short8 (8 bf16) from 8 fp32
__device__ __forceinline__ short8 pack8(const float4 t0, const float4 t1) {
    union { uint32_t u[4]; short8 s; } r;
    r.u[0] = pk2bf(t0.x, t0.y); r.u[1] = pk2bf(t0.z, t0.w);
    r.u[2] = pk2bf(t1.x, t1.y); r.u[3] = pk2bf(t1.z, t1.w);
    return r.s;
}

__device__ __forceinline__ float bf_lo(uint32_t u) {
    union { uint32_t u; float f; } v; v.u = u << 16; return v.f;
}
__device__ __forceinline__ float bf_hi(uint32_t u) {
    union { uint32_t u; float f; } v; v.u = u & 0xffff0000u; return v.f;
}

// ---------------------------------------------------------------------------
// One-time weight conversion fp32 -> bf16: Wq, Wk, Wv (64x64), Wo (512x512)
// ---------------------------------------------------------------------------
__global__ __launch_bounds__(256) void prep_weights(const float* __restrict__ Wq, const float* __restrict__ Wk,
                                                    const float* __restrict__ Wv, const float* __restrict__ Wo,
                                                    short* __restrict__ WqB, short* __restrict__ WkB,
                                                    short* __restrict__ WvB, short* __restrict__ WoB) {
    int i = blockIdx.x * 256 + threadIdx.x;   // float4 index, 68608 total
    const float* src; short* dst; int off;
    if (i < 1024)      { src = Wq; dst = WqB; off = i; }
    else if (i < 2048) { src = Wk; dst = WkB; off = i - 1024; }
    else if (i < 3072) { src = Wv; dst = WvB; off = i - 2048; }
    else               { src = Wo; dst = WoB; off = i - 3072; }
    float4 t = reinterpret_cast<const float4*>(src)[off];
    uint2 d; d.x = pk2bf(t.x, t.y); d.y = pk2bf(t.z, t.w);
    reinterpret_cast<uint2*>(dst)[off] = d;
}

// ---------------------------------------------------------------------------
// Fused projections, one launch.
//  blocks [0,2048):    q  (transposed compute: A=Wq, B=X rows; packed stores)
//  blocks [2048,4096): k  (same)
//  blocks [4096,6144): v  (A=X, B=Wv; packed transposed stores -> vT[f][l])
// ---------------------------------------------------------------------------
__global__ __launch_bounds__(256) void proj_fused(const float* __restrict__ query, const float* __restrict__ key,
                                                  const float* __restrict__ value,
                                                  const short* __restrict__ WqB, const short* __restrict__ WkB,
                                                  const short* __restrict__ WvB,
                                                  short* __restrict__ Oq, short* __restrict__ Ok, short* __restrict__ OvT) {
    const int id = blockIdx.x;
    const int lane = threadIdx.x & 63;
    const int wave = threadIdx.x >> 6;
    const int quad = lane >> 4;
    const int c    = lane & 15;

    if (id < 4096) {
        const bool isq = id < 2048;
        const float* X = isq ? query : key;
        const short* W = isq ? WqB : WkB;
        short* O = isq ? Oq : Ok;
        const float oscale = isq ? QSCALE : 1.0f;
        const int xid = isq ? id : id - 2048;
        const long r0 = (long)xid * 64 + wave * 16;

        short8 xb[2];
#pragma unroll
        for (int kk = 0; kk < 2; ++kk) {
            const float* src = X + (r0 + c) * 64 + kk * 32 + quad * 8;
            xb[kk] = pack8(*reinterpret_cast<const float4*>(src), *reinterpret_cast<const float4*>(src + 4));
        }

        f32x4 acc[4];
#pragma unroll
        for (int ft = 0; ft < 4; ++ft) { acc[ft][0]=0.f; acc[ft][1]=0.f; acc[ft][2]=0.f; acc[ft][3]=0.f; }

#pragma unroll
        for (int ft = 0; ft < 4; ++ft)
#pragma unroll
            for (int kk = 0; kk < 2; ++kk) {
                short8 wa = *reinterpret_cast<const short8*>(W + (ft * 16 + c) * 64 + kk * 32 + quad * 8);
                acc[ft] = __builtin_amdgcn_mfma_f32_16x16x32_bf16(wa, xb[kk], acc[ft], 0, 0, 0);
            }

#pragma unroll
        for (int ft = 0; ft < 4; ++ft) {
            uint2 d;
            d.x = pk2bf(acc[ft][0] * oscale, acc[ft][1] * oscale);
            d.y = pk2bf(acc[ft][2] * oscale, acc[ft][3] * oscale);
            *reinterpret_cast<uint2*>(O + (r0 + c) * 64 + ft * 16 + quad * 4) = d;
        }
    } else {
        const int vid = id - 4096;
        const int bh = vid >> 5, lt = vid & 31;
        const int b = bh >> 3, h = bh & 7;
        const int l0 = lt * 64 + wave * 16;

        short8 xa[2];
#pragma unroll
        for (int kk = 0; kk < 2; ++kk) {
            const float* src = value + ((long)(b * LL + l0 + c) * EE + h * 64) + kk * 32 + quad * 8;
            xa[kk] = pack8(*reinterpret_cast<const float4*>(src), *reinterpret_cast<const float4*>(src + 4));
        }

        f32x4 acc[4];
#pragma unroll
        for (int nt = 0; nt < 4; ++nt) { acc[nt][0]=0.f; acc[nt][1]=0.f; acc[nt][2]=0.f; acc[nt][3]=0.f; }

#pragma unroll
        for (int nt = 0; nt < 4; ++nt)
#pragma unroll
            for (int kk = 0; kk < 2; ++kk) {
                short8 wb = *reinterpret_cast<const short8*>(WvB + (nt * 16 + c) * 64 + kk * 32 + quad * 8);
                acc[nt] = __builtin_amdgcn_mfma_f32_16x16x32_bf16(xa[kk], wb, acc[nt], 0, 0, 0);
            }

#pragma unroll
        for (int nt = 0; nt < 4; ++nt) {
            uint2 d;
            d.x = pk2bf(acc[nt][0], acc[nt][1]);
            d.y = pk2bf(acc[nt][2], acc[nt][3]);
            *reinterpret_cast<uint2*>(OvT + ((long)bh * 64 + nt * 16 + c) * LL + l0 + quad * 4) = d;
        }
    }
}

// ---------------------------------------------------------------------------
// Attention, no-max softmax, ZERO LDS, SPLIT-K over keys (2 splits of 1024).
// R3 per-wave shape kept EXACTLY (64 q-rows/wave, 120 VGPR, 2 t-streams of
// ILP): R4 showed that shrinking the wave tile squeezes registers (VGPR 64)
// and halves flops/byte -> 2x regression. Split-K doubles resident waves
// (1024 blocks -> 4 blocks/CU -> 4 waves/SIMD) at IDENTICAL per-wave code.
// Partials are linear (no-max softmax): store unnormalized O (bf16) + l
// (f32); combine_attn sums and normalizes.
// S^T = K Q^T  (C: col=q (lane&31), row=key (reg&3)+8*(reg>>2)+4*hl)
// P^T B-fragments IN-REGISTER via v_permlane32_swap_b32 (verified R3):
//   rA = swap(xd[even][d], xd[odd][d]); pb.u[d]=rA[0]; pb.u[2+d]=rA[1].
// ---------------------------------------------------------------------------
__global__ __launch_bounds__(256, 4) void attn_kernel(const short* __restrict__ Q, const short* __restrict__ K,
                                                      const short* __restrict__ VT, short* __restrict__ Opart,
                                                      float* __restrict__ lws) {
    const int lane = threadIdx.x & 63;
    const int wave = threadIdx.x >> 6;
    const int hl = lane >> 5;          // lane half (bit 5)
    const int c  = lane & 31;          // col within 32 (q-index / A-row)
    const int bh = blockIdx.x & 63;    // consecutive blocks -> different bh
    const int qs = (blockIdx.x >> 6) & 7;   // 0..7
    const int split = blockIdx.x >> 9;      // 0..1 (key range)
    const int b = bh >> 3, head = bh & 7;
    const int q0 = qs * 256 + wave * 64;

    // Q B-fragments (S^T B-operand): B[k=feat][col=q]; k = ks*16 + hl*8 + j
    short8 aq[2][4];
#pragma unroll
    for (int t = 0; t < 2; ++t)
#pragma unroll
        for (int ks = 0; ks < 4; ++ks)
            aq[t][ks] = *reinterpret_cast<const short8*>(Q + ((long)bh * LL + q0 + t * 32 + c) * 64 + ks * 16 + hl * 8);

    f32x16 of[2][2];
#pragma unroll
    for (int t = 0; t < 2; ++t)
#pragma unroll
        for (int ft = 0; ft < 2; ++ft)
#pragma unroll
            for (int i = 0; i < 16; ++i) of[t][ft][i] = 0.f;
    float l[2] = {0.f, 0.f};

    const short* Kb = K  + (long)bh * LL * 64;
    const short* Vb = VT + (long)bh * 64 * LL;

    const int kb0 = split * 1024;
    for (int kb = kb0; kb < kb0 + 1024; kb += 64) {
        // K A-fragments: A[row=key][k=feat]  (2 key-tiles of 32, 4 feat k-slices)
        // V^T A-fragments: A[row=feat][k=key] (2 feat-tiles of 32, 4 key k-slices)
        short8 kf[2][4], vf[2][4];
#pragma unroll
        for (int kt = 0; kt < 2; ++kt)
#pragma unroll
            for (int ks = 0; ks < 4; ++ks)
                kf[kt][ks] = *reinterpret_cast<const short8*>(Kb + (long)(kb + kt * 32 + c) * 64 + ks * 16 + hl * 8);
#pragma unroll
        for (int ft = 0; ft < 2; ++ft)
#pragma unroll
            for (int kk = 0; kk < 4; ++kk)
                vf[ft][kk] = *reinterpret_cast<const short8*>(Vb + (long)(ft * 32 + c) * LL + kb + kk * 16 + hl * 8);

#pragma unroll
        for (int t = 0; t < 2; ++t)
#pragma unroll
            for (int kt = 0; kt < 2; ++kt) {
                // S^T tile: 32 keys x 32 q, K-dim = 64 feats = 4 chained MFMAs
                f32x16 s;
#pragma unroll
                for (int i = 0; i < 16; ++i) s[i] = 0.f;
#pragma unroll
                for (int ks = 0; ks < 4; ++ks)
                    s = __builtin_amdgcn_mfma_f32_32x32x16_bf16(kf[kt][ks], aq[t][ks], s, 0, 0, 0);

                // exp2, accumulate denom, pack to bf16 pairs
                uint32_t xd[4][2];
                float lac = 0.f;
#pragma unroll
                for (int g = 0; g < 4; ++g) {
                    const float p0 = __builtin_amdgcn_exp2f(s[4 * g + 0]);
                    const float p1 = __builtin_amdgcn_exp2f(s[4 * g + 1]);
                    const float p2 = __builtin_amdgcn_exp2f(s[4 * g + 2]);
                    const float p3 = __builtin_amdgcn_exp2f(s[4 * g + 3]);
                    lac += (p0 + p1) + (p2 + p3);
                    xd[g][0] = pk2bf(p0, p1);
                    xd[g][1] = pk2bf(p2, p3);
                }
                l[t] += lac;

                // build P^T B-fragments (16-key k-tiles) via permlane32_swap,
                // feed PV immediately: O^T[feat][q] += V^T[feat][key] P^T[key][q]
#pragma unroll
                for (int kt2 = 0; kt2 < 2; ++kt2) {
                    u32x2v rA = __builtin_amdgcn_permlane32_swap(xd[2 * kt2][0], xd[2 * kt2 + 1][0], false, false);
                    u32x2v rB = __builtin_amdgcn_permlane32_swap(xd[2 * kt2][1], xd[2 * kt2 + 1][1], false, false);
                    union { uint32_t u[4]; short8 s8; } pb;
                    pb.u[0] = rA[0]; pb.u[1] = rB[0]; pb.u[2] = rA[1]; pb.u[3] = rB[1];
                    const int kk = kt * 2 + kt2;
                    of[t][0] = __builtin_amdgcn_mfma_f32_32x32x16_bf16(vf[0][kk], pb.s8, of[t][0], 0, 0, 0);
                    of[t][1] = __builtin_amdgcn_mfma_f32_32x32x16_bf16(vf[1][kk], pb.s8, of[t][1], 0, 0, 0);
                }
            }
    }

    // denom partials: reduce across lane halves, store (hl==0 lanes)
#pragma unroll
    for (int t = 0; t < 2; ++t) l[t] += __shfl_xor(l[t], 32);
    if (hl == 0) {
        float* lp = lws + (long)split * (64 * LL) + bh * LL + q0;
        lp[c] = l[0];
        lp[32 + c] = l[1];
    }

    // epilogue: store UNNORMALIZED partial O as bf16.
    // of[t][ft] C-layout: col=c (q), row = 8g + 4hl + r (feat within 32)
    short* Od = Opart + (long)split * (BB * LL * EE);
#pragma unroll
    for (int t = 0; t < 2; ++t) {
        const long row = (long)b * LL + q0 + t * 32 + c;
#pragma unroll
        for (int ft = 0; ft < 2; ++ft)
#pragma unroll
            for (int g = 0; g < 4; ++g) {
                uint2 d;
                d.x = pk2bf(of[t][ft][4 * g + 0], of[t][ft][4 * g + 1]);
                d.y = pk2bf(of[t][ft][4 * g + 2], of[t][ft][4 * g + 3]);
                *reinterpret_cast<uint2*>(Od + row * EE + head * 64 + ft * 32 + g * 8 + hl * 4) = d;
            }
    }
}

// ---------------------------------------------------------------------------
// Combine split-K partials: attn = (O0 + O1) / (l0 + l1), bf16 out.
// One thread = one short8 (8 feats, never crosses a head boundary).
// ---------------------------------------------------------------------------
__global__ __launch_bounds__(256) void combine_attn(const short* __restrict__ Opart, const float* __restrict__ lws,
                                                    short* __restrict__ Oattn) {
    const int g = blockIdx.x * 256 + threadIdx.x;   // short8 idx, 16384*64 total
    const int row = g >> 6;                         // b*2048 + r
    const int f0  = (g & 63) * 8;
    const int bh  = ((row >> 11) << 3) + (f0 >> 6);
    const int rl  = row & (LL - 1);
    const float l0 = lws[(long)bh * LL + rl];
    const float l1 = lws[(long)64 * LL + (long)bh * LL + rl];
    const float inv = 1.0f / (l0 + l1);

    union { short8 s; uint32_t u[4]; } x0, x1, o;
    x0.s = reinterpret_cast<const short8*>(Opart)[g];
    x1.s = reinterpret_cast<const short8*>(Opart + (long)BB * LL * EE)[g];
#pragma unroll
    for (int d = 0; d < 4; ++d) {
        const float lo = bf_lo(x0.u[d]) + bf_lo(x1.u[d]);
        const float hi = bf_hi(x0.u[d]) + bf_hi(x1.u[d]);
        o.u[d] = pk2bf(lo * inv, hi * inv);
    }
    reinterpret_cast<short8*>(Oattn)[g] = o.s;
}

// ---------------------------------------------------------------------------
// out^T-compute = Wo . attn^T: lane holds 4 consecutive out-features -> float4
// ---------------------------------------------------------------------------
__global__ __launch_bounds__(256) void out_proj(const short* __restrict__ A, const short* __restrict__ WoB,
                                                const float* __restrict__ bo, float* __restrict__ out) {
    const int lane = threadIdx.x & 63;
    const int wave = threadIdx.x >> 6;
    const int quad = lane >> 4;
    const int c    = lane & 15;
    const int nb = blockIdx.x;   // 0..7 feature block
    const int rb = blockIdx.y;   // 0..255
    const long r0 = (long)rb * 64 + wave * 16;

    f32x4 acc[4];
#pragma unroll
    for (int ft = 0; ft < 4; ++ft) { acc[ft][0]=0.f; acc[ft][1]=0.f; acc[ft][2]=0.f; acc[ft][3]=0.f; }

    for (int ks = 0; ks < 16; ++ks) {
        short8 bfr = *reinterpret_cast<const short8*>(A + (r0 + c) * EE + ks * 32 + quad * 8);
#pragma unroll
        for (int ft = 0; ft < 4; ++ft) {
            short8 afr = *reinterpret_cast<const short8*>(WoB + ((long)(nb * 64 + ft * 16 + c)) * EE + ks * 32 + quad * 8);
            acc[ft] = __builtin_amdgcn_mfma_f32_16x16x32_bf16(afr, bfr, acc[ft], 0, 0, 0);
        }
    }

#pragma unroll
    for (int ft = 0; ft < 4; ++ft) {
        float4 bias = *reinterpret_cast<const float4*>(bo + nb * 64 + ft * 16 + quad * 4);
        float4 res;
        res.x = acc[ft][0] + bias.x; res.y = acc[ft][1] + bias.y;
        res.z = acc[ft][2] + bias.z; res.w = acc[ft][3] + bias.w;
        *reinterpret_cast<float4*>(out + (r0 + c) * EE + nb * 64 + ft * 16 + quad * 4) = res;
    }
}

extern "C" void kernel_launch(void* const* d_in, const int* in_sizes, int n_in,
                              void* d_out, int out_size, void* d_ws, size_t ws_size,
                              hipStream_t stream) {
    const float* query = (const float*)d_in[0];
    const float* key   = (const float*)d_in[1];
    const float* value = (const float*)d_in[2];
    const float* Wq    = (const float*)d_in[3];
    const float* Wk    = (const float*)d_in[4];
    const float* Wv    = (const float*)d_in[5];
    const float* Wo    = (const float*)d_in[6];
    const float* bo    = (const float*)d_in[7];
    float* out = (float*)d_out;

    char* ws = (char*)d_ws;
    const size_t SZ = 16777216;             // B*H*L*64 bf16 bytes
    short* q_ws    = (short*)(ws);
    short* k_ws    = (short*)(ws + SZ);
    short* vT_ws   = (short*)(ws + 2 * SZ);
    short* op_ws   = (short*)(ws + 3 * SZ);            // 2 splits x 16 MiB
    float* l_ws    = (float*)(ws + 5 * SZ);            // 2 x 64 x 2048 f32 = 1 MiB
    short* attn_ws = q_ws;                             // alias: Q dead after attn
    short* wo_ws   = (short*)(ws + 5 * SZ + 2097152);  // 512 KiB
    short* wq_ws   = (short*)(ws + 5 * SZ + 2097152 + 524288);
    short* wk_ws   = (short*)(ws + 5 * SZ + 2097152 + 532480);
    short* wv_ws   = (short*)(ws + 5 * SZ + 2097152 + 540672);

    prep_weights<<<268, 256, 0, stream>>>(Wq, Wk, Wv, Wo, wq_ws, wk_ws, wv_ws, wo_ws);
    proj_fused<<<6144, 256, 0, stream>>>(query, key, value, wq_ws, wk_ws, wv_ws, q_ws, k_ws, vT_ws);
    attn_kernel<<<1024, 256, 0, stream>>>(q_ws, k_ws, vT_ws, op_ws, l_ws);
    combine_attn<<<4096, 256, 0, stream>>>(op_ws, l_ws, attn_ws);
    out_proj<<<dim3(8, 256), 256, 0, stream>>>(attn_ws, wo_ws, bo, out);
}

// Round 6
// 436.370 us; speedup vs baseline: 1.6332x; 1.6332x over previous
//
#include <hip/hip_runtime.h>
#include <stdint.h>

#define BB 8
#define LL 2048
#define EE 512
#define HH 8
#define DD 64

typedef __attribute__((ext_vector_type(8))) short short8;
typedef __attribute__((ext_vector_type(4))) float f32x4;
typedef __attribute__((ext_vector_type(16))) float f32x16;
typedef __attribute__((ext_vector_type(2))) unsigned int u32x2v;

// q pre-scale: log2(e)/sqrt(512), so attention uses bare exp2
#define QSCALE 0.06376435773361453f

// pack two f32 -> two bf16 (round-half-up) in one dword: low=a, high=b
__device__ __forceinline__ uint32_t pk2bf(float a, float b) {
    union { float f; uint32_t u; } va, vb; va.f = a; vb.f = b;
    return __builtin_amdgcn_perm(vb.u + 0x8000u, va.u + 0x8000u, 0x07060302u);
}

// build a short8 (8 bf16) from 8 fp32
__device__ __forceinline__ short8 pack8(const float4 t0, const float4 t1) {
    union { uint32_t u[4]; short8 s; } r;
    r.u[0] = pk2bf(t0.x, t0.y); r.u[1] = pk2bf(t0.z, t0.w);
    r.u[2] = pk2bf(t1.x, t1.y); r.u[3] = pk2bf(t1.z, t1.w);
    return r.s;
}

// ---------------------------------------------------------------------------
// One-time weight conversion fp32 -> bf16: Wq, Wk, Wv (64x64), Wo (512x512)
// ---------------------------------------------------------------------------
__global__ __launch_bounds__(256) void prep_weights(const float* __restrict__ Wq, const float* __restrict__ Wk,
                                                    const float* __restrict__ Wv, const float* __restrict__ Wo,
                                                    short* __restrict__ WqB, short* __restrict__ WkB,
                                                    short* __restrict__ WvB, short* __restrict__ WoB) {
    int i = blockIdx.x * 256 + threadIdx.x;   // float4 index, 68608 total
    const float* src; short* dst; int off;
    if (i < 1024)      { src = Wq; dst = WqB; off = i; }
    else if (i < 2048) { src = Wk; dst = WkB; off = i - 1024; }
    else if (i < 3072) { src = Wv; dst = WvB; off = i - 2048; }
    else               { src = Wo; dst = WoB; off = i - 3072; }
    float4 t = reinterpret_cast<const float4*>(src)[off];
    uint2 d; d.x = pk2bf(t.x, t.y); d.y = pk2bf(t.z, t.w);
    reinterpret_cast<uint2*>(dst)[off] = d;
}

// ---------------------------------------------------------------------------
// Fused projections, one launch.
//  blocks [0,2048):    q  (transposed compute: A=Wq, B=X rows; packed stores)
//  blocks [2048,4096): k  (same)
//  blocks [4096,6144): v  (A=X, B=Wv; packed transposed stores -> vT[f][l])
// ---------------------------------------------------------------------------
__global__ __launch_bounds__(256) void proj_fused(const float* __restrict__ query, const float* __restrict__ key,
                                                  const float* __restrict__ value,
                                                  const short* __restrict__ WqB, const short* __restrict__ WkB,
                                                  const short* __restrict__ WvB,
                                                  short* __restrict__ Oq, short* __restrict__ Ok, short* __restrict__ OvT) {
    const int id = blockIdx.x;
    const int lane = threadIdx.x & 63;
    const int wave = threadIdx.x >> 6;
    const int quad = lane >> 4;
    const int c    = lane & 15;

    if (id < 4096) {
        const bool isq = id < 2048;
        const float* X = isq ? query : key;
        const short* W = isq ? WqB : WkB;
        short* O = isq ? Oq : Ok;
        const float oscale = isq ? QSCALE : 1.0f;
        const int xid = isq ? id : id - 2048;
        const long r0 = (long)xid * 64 + wave * 16;

        short8 xb[2];
#pragma unroll
        for (int kk = 0; kk < 2; ++kk) {
            const float* src = X + (r0 + c) * 64 + kk * 32 + quad * 8;
            xb[kk] = pack8(*reinterpret_cast<const float4*>(src), *reinterpret_cast<const float4*>(src + 4));
        }

        f32x4 acc[4];
#pragma unroll
        for (int ft = 0; ft < 4; ++ft) { acc[ft][0]=0.f; acc[ft][1]=0.f; acc[ft][2]=0.f; acc[ft][3]=0.f; }

#pragma unroll
        for (int ft = 0; ft < 4; ++ft)
#pragma unroll
            for (int kk = 0; kk < 2; ++kk) {
                short8 wa = *reinterpret_cast<const short8*>(W + (ft * 16 + c) * 64 + kk * 32 + quad * 8);
                acc[ft] = __builtin_amdgcn_mfma_f32_16x16x32_bf16(wa, xb[kk], acc[ft], 0, 0, 0);
            }

#pragma unroll
        for (int ft = 0; ft < 4; ++ft) {
            uint2 d;
            d.x = pk2bf(acc[ft][0] * oscale, acc[ft][1] * oscale);
            d.y = pk2bf(acc[ft][2] * oscale, acc[ft][3] * oscale);
            *reinterpret_cast<uint2*>(O + (r0 + c) * 64 + ft * 16 + quad * 4) = d;
        }
    } else {
        const int vid = id - 4096;
        const int bh = vid >> 5, lt = vid & 31;
        const int b = bh >> 3, h = bh & 7;
        const int l0 = lt * 64 + wave * 16;

        short8 xa[2];
#pragma unroll
        for (int kk = 0; kk < 2; ++kk) {
            const float* src = value + ((long)(b * LL + l0 + c) * EE + h * 64) + kk * 32 + quad * 8;
            xa[kk] = pack8(*reinterpret_cast<const float4*>(src), *reinterpret_cast<const float4*>(src + 4));
        }

        f32x4 acc[4];
#pragma unroll
        for (int nt = 0; nt < 4; ++nt) { acc[nt][0]=0.f; acc[nt][1]=0.f; acc[nt][2]=0.f; acc[nt][3]=0.f; }

#pragma unroll
        for (int nt = 0; nt < 4; ++nt)
#pragma unroll
            for (int kk = 0; kk < 2; ++kk) {
                short8 wb = *reinterpret_cast<const short8*>(WvB + (nt * 16 + c) * 64 + kk * 32 + quad * 8);
                acc[nt] = __builtin_amdgcn_mfma_f32_16x16x32_bf16(xa[kk], wb, acc[nt], 0, 0, 0);
            }

#pragma unroll
        for (int nt = 0; nt < 4; ++nt) {
            uint2 d;
            d.x = pk2bf(acc[nt][0], acc[nt][1]);
            d.y = pk2bf(acc[nt][2], acc[nt][3]);
            *reinterpret_cast<uint2*>(OvT + ((long)bh * 64 + nt * 16 + c) * LL + l0 + quad * 4) = d;
        }
    }
}

// ---------------------------------------------------------------------------
// Attention, no-max softmax, ZERO LDS. R3 structure (64 q-rows/wave, 256
// q-rows/block, 512 blocks, launch_bounds(256,2)) + REGISTER SOFTWARE
// PIPELINE. R4/R5 lesson: wave state ~230 regs => structurally 2 waves/SIMD;
// do NOT force 4 (R5: launch_bounds(256,4) -> 2GB scratch spill traffic).
// R3 postmortem arithmetic: 10.1k cyc/tile ~= 16 loads x ~600cy serialized;
// issue-limited work is only ~580cy. Fix = ILP: batch all 16 tile loads +
// prefetch next tile's K a full tile ahead (kfA/kfB double buffer, static
// names), sched_barrier(0) pins the load batch above the MFMA stream.
// S^T = K Q^T  (C: col=q (lane&31), row=key (reg&3)+8*(reg>>2)+4*hl)
// P^T B-fragments IN-REGISTER via v_permlane32_swap_b32 (verified R3):
//   rA = swap(xd[even][d], xd[odd][d]); pb.u[d]=rA[0]; pb.u[2+d]=rA[1].
// O^T = V^T P^T, accumulated in f32x16; epilogue scales by 1/l.
// ---------------------------------------------------------------------------
#define LOADKF(dst, kbrow) { \
    _Pragma("unroll") for (int kt_ = 0; kt_ < 2; ++kt_) \
    _Pragma("unroll") for (int ks_ = 0; ks_ < 4; ++ks_) \
        dst[kt_][ks_] = *reinterpret_cast<const short8*>(Kb + (long)((kbrow) + kt_ * 32 + c) * 64 + ks_ * 16 + hl * 8); }

#define LOADVF(dst, kbcol) { \
    _Pragma("unroll") for (int ft_ = 0; ft_ < 2; ++ft_) \
    _Pragma("unroll") for (int kk_ = 0; kk_ < 4; ++kk_) \
        dst[ft_][kk_] = *reinterpret_cast<const short8*>(Vb + (long)(ft_ * 32 + c) * LL + (kbcol) + kk_ * 16 + hl * 8); }

#define TILE(kf, vfr) { \
    _Pragma("unroll") for (int t = 0; t < 2; ++t) \
    _Pragma("unroll") for (int kt = 0; kt < 2; ++kt) { \
        f32x16 s; \
        _Pragma("unroll") for (int i = 0; i < 16; ++i) s[i] = 0.f; \
        _Pragma("unroll") for (int ks = 0; ks < 4; ++ks) \
            s = __builtin_amdgcn_mfma_f32_32x32x16_bf16(kf[kt][ks], aq[t][ks], s, 0, 0, 0); \
        uint32_t xd[4][2]; float lac = 0.f; \
        _Pragma("unroll") for (int g = 0; g < 4; ++g) { \
            const float p0 = __builtin_amdgcn_exp2f(s[4 * g + 0]); \
            const float p1 = __builtin_amdgcn_exp2f(s[4 * g + 1]); \
            const float p2 = __builtin_amdgcn_exp2f(s[4 * g + 2]); \
            const float p3 = __builtin_amdgcn_exp2f(s[4 * g + 3]); \
            lac += (p0 + p1) + (p2 + p3); \
            xd[g][0] = pk2bf(p0, p1); xd[g][1] = pk2bf(p2, p3); \
        } \
        l[t] += lac; \
        _Pragma("unroll") for (int kt2 = 0; kt2 < 2; ++kt2) { \
            u32x2v rA = __builtin_amdgcn_permlane32_swap(xd[2 * kt2][0], xd[2 * kt2 + 1][0], false, false); \
            u32x2v rB = __builtin_amdgcn_permlane32_swap(xd[2 * kt2][1], xd[2 * kt2 + 1][1], false, false); \
            union { uint32_t u[4]; short8 s8; } pb; \
            pb.u[0] = rA[0]; pb.u[1] = rB[0]; pb.u[2] = rA[1]; pb.u[3] = rB[1]; \
            const int kk = kt * 2 + kt2; \
            of[t][0] = __builtin_amdgcn_mfma_f32_32x32x16_bf16(vfr[0][kk], pb.s8, of[t][0], 0, 0, 0); \
            of[t][1] = __builtin_amdgcn_mfma_f32_32x32x16_bf16(vfr[1][kk], pb.s8, of[t][1], 0, 0, 0); \
        } \
    } }

__global__ __launch_bounds__(256, 2) void attn_kernel(const short* __restrict__ Q, const short* __restrict__ K,
                                                      const short* __restrict__ VT, short* __restrict__ Oattn) {
    const int lane = threadIdx.x & 63;
    const int wave = threadIdx.x >> 6;
    const int hl = lane >> 5;          // lane half (bit 5)
    const int c  = lane & 31;          // col within 32 (q-index / A-row)
    const int bh = blockIdx.x & 63;    // consecutive blocks -> different bh
    const int qs = blockIdx.x >> 6;    // 0..7
    const int b = bh >> 3, head = bh & 7;
    const int q0 = qs * 256 + wave * 64;

    // Q B-fragments (S^T B-operand): B[k=feat][col=q]; k = ks*16 + hl*8 + j
    short8 aq[2][4];
#pragma unroll
    for (int t = 0; t < 2; ++t)
#pragma unroll
        for (int ks = 0; ks < 4; ++ks)
            aq[t][ks] = *reinterpret_cast<const short8*>(Q + ((long)bh * LL + q0 + t * 32 + c) * 64 + ks * 16 + hl * 8);

    f32x16 of[2][2];
#pragma unroll
    for (int t = 0; t < 2; ++t)
#pragma unroll
        for (int ft = 0; ft < 2; ++ft)
#pragma unroll
            for (int i = 0; i < 16; ++i) of[t][ft][i] = 0.f;
    float l[2] = {0.f, 0.f};

    const short* Kb = K  + (long)bh * LL * 64;
    const short* Vb = VT + (long)bh * 64 * LL;

    // register software pipeline: kfA/kfB = K-tile double buffer (static
    // names, rule #20); vf reloaded per half-iteration (dead after TILE).
    short8 kfA[2][4], kfB[2][4], vf[2][4];
    LOADKF(kfA, 0);

#pragma unroll 1
    for (int kb = 0; kb < LL; kb += 128) {
        // ---- tile kb: consume kfA, prefetch K(kb+64) ----
        LOADVF(vf, kb);
        LOADKF(kfB, kb + 64);
        __builtin_amdgcn_sched_barrier(0);   // pin load batch above MFMAs
        TILE(kfA, vf);
        // ---- tile kb+64: consume kfB, prefetch K(kb+128, wrapped) ----
        LOADVF(vf, kb + 64);
        LOADKF(kfA, (kb + 128) & (LL - 1));  // wrap: dummy re-load of tile 0 on last iter
        __builtin_amdgcn_sched_barrier(0);
        TILE(kfB, vf);
    }

    // denom: lane holds partial over its half's keys; one swap finishes it
    float inv[2];
#pragma unroll
    for (int t = 0; t < 2; ++t) {
        l[t] += __shfl_xor(l[t], 32);
        inv[t] = 1.0f / l[t];
    }

    // epilogue: of[t][ft] C-layout: col=c (q), row = 8g + 4hl + r (feat within 32)
#pragma unroll
    for (int t = 0; t < 2; ++t) {
        const long row = (long)b * LL + q0 + t * 32 + c;
#pragma unroll
        for (int ft = 0; ft < 2; ++ft)
#pragma unroll
            for (int g = 0; g < 4; ++g) {
                const float v0 = of[t][ft][4 * g + 0] * inv[t], v1 = of[t][ft][4 * g + 1] * inv[t];
                const float v2 = of[t][ft][4 * g + 2] * inv[t], v3 = of[t][ft][4 * g + 3] * inv[t];
                uint2 d; d.x = pk2bf(v0, v1); d.y = pk2bf(v2, v3);
                *reinterpret_cast<uint2*>(Oattn + row * EE + head * 64 + ft * 32 + g * 8 + hl * 4) = d;
            }
    }
}

// ---------------------------------------------------------------------------
// out^T-compute = Wo . attn^T: lane holds 4 consecutive out-features -> float4
// ---------------------------------------------------------------------------
__global__ __launch_bounds__(256) void out_proj(const short* __restrict__ A, const short* __restrict__ WoB,
                                                const float* __restrict__ bo, float* __restrict__ out) {
    const int lane = threadIdx.x & 63;
    const int wave = threadIdx.x >> 6;
    const int quad = lane >> 4;
    const int c    = lane & 15;
    const int nb = blockIdx.x;   // 0..7 feature block
    const int rb = blockIdx.y;   // 0..255
    const long r0 = (long)rb * 64 + wave * 16;

    f32x4 acc[4];
#pragma unroll
    for (int ft = 0; ft < 4; ++ft) { acc[ft][0]=0.f; acc[ft][1]=0.f; acc[ft][2]=0.f; acc[ft][3]=0.f; }

    for (int ks = 0; ks < 16; ++ks) {
        short8 bfr = *reinterpret_cast<const short8*>(A + (r0 + c) * EE + ks * 32 + quad * 8);
#pragma unroll
        for (int ft = 0; ft < 4; ++ft) {
            short8 afr = *reinterpret_cast<const short8*>(WoB + ((long)(nb * 64 + ft * 16 + c)) * EE + ks * 32 + quad * 8);
            acc[ft] = __builtin_amdgcn_mfma_f32_16x16x32_bf16(afr, bfr, acc[ft], 0, 0, 0);
        }
    }

#pragma unroll
    for (int ft = 0; ft < 4; ++ft) {
        float4 bias = *reinterpret_cast<const float4*>(bo + nb * 64 + ft * 16 + quad * 4);
        float4 res;
        res.x = acc[ft][0] + bias.x; res.y = acc[ft][1] + bias.y;
        res.z = acc[ft][2] + bias.z; res.w = acc[ft][3] + bias.w;
        *reinterpret_cast<float4*>(out + (r0 + c) * EE + nb * 64 + ft * 16 + quad * 4) = res;
    }
}

extern "C" void kernel_launch(void* const* d_in, const int* in_sizes, int n_in,
                              void* d_out, int out_size, void* d_ws, size_t ws_size,
                              hipStream_t stream) {
    const float* query = (const float*)d_in[0];
    const float* key   = (const float*)d_in[1];
    const float* value = (const float*)d_in[2];
    const float* Wq    = (const float*)d_in[3];
    const float* Wk    = (const float*)d_in[4];
    const float* Wv    = (const float*)d_in[5];
    const float* Wo    = (const float*)d_in[6];
    const float* bo    = (const float*)d_in[7];
    float* out = (float*)d_out;

    char* ws = (char*)d_ws;
    const size_t SZ = 16777216;             // B*H*L*64 bf16 bytes
    short* q_ws    = (short*)(ws);
    short* k_ws    = (short*)(ws + SZ);
    short* vT_ws   = (short*)(ws + 2 * SZ);
    short* attn_ws = (short*)(ws + 3 * SZ);
    short* wo_ws   = (short*)(ws + 4 * SZ);            // 512 KiB
    short* wq_ws   = (short*)(ws + 4 * SZ + 524288);   // 8 KiB each
    short* wk_ws   = (short*)(ws + 4 * SZ + 532480);
    short* wv_ws   = (short*)(ws + 4 * SZ + 540672);

    prep_weights<<<268, 256, 0, stream>>>(Wq, Wk, Wv, Wo, wq_ws, wk_ws, wv_ws, wo_ws);
    proj_fused<<<6144, 256, 0, stream>>>(query, key, value, wq_ws, wk_ws, wv_ws, q_ws, k_ws, vT_ws);
    attn_kernel<<<512, 256, 0, stream>>>(q_ws, k_ws, vT_ws, attn_ws);
    out_proj<<<dim3(8, 256), 256, 0, stream>>>(attn_ws, wo_ws, bo, out);
}

// Round 7
// 318.726 us; speedup vs baseline: 2.2360x; 1.3691x over previous
//
#include <hip/hip_runtime.h>
#include <stdint.h>

#define BB 8
#define LL 2048
#define EE 512
#define HH 8
#define DD 64

typedef __attribute__((ext_vector_type(8))) short short8;
typedef __attribute__((ext_vector_type(4))) float f32x4;
typedef __attribute__((ext_vector_type(16))) float f32x16;
typedef __attribute__((ext_vector_type(2))) unsigned int u32x2v;

// q pre-scale: log2(e)/sqrt(512), so attention uses bare exp2
#define QSCALE 0.06376435773361453f

// pack two f32 -> two bf16 (round-half-up) in one dword: low=a, high=b
__device__ __forceinline__ uint32_t pk2bf(float a, float b) {
    union { float f; uint32_t u; } va, vb; va.f = a; vb.f = b;
    return __builtin_amdgcn_perm(vb.u + 0x8000u, va.u + 0x8000u, 0x07060302u);
}

// build a short8 (8 bf16) from 8 fp32
__device__ __forceinline__ short8 pack8(const float4 t0, const float4 t1) {
    union { uint32_t u[4]; short8 s; } r;
    r.u[0] = pk2bf(t0.x, t0.y); r.u[1] = pk2bf(t0.z, t0.w);
    r.u[2] = pk2bf(t1.x, t1.y); r.u[3] = pk2bf(t1.z, t1.w);
    return r.s;
}

// ---------------------------------------------------------------------------
// One-time weight conversion fp32 -> bf16: Wq, Wk, Wv (64x64), Wo (512x512)
// ---------------------------------------------------------------------------
__global__ __launch_bounds__(256) void prep_weights(const float* __restrict__ Wq, const float* __restrict__ Wk,
                                                    const float* __restrict__ Wv, const float* __restrict__ Wo,
                                                    short* __restrict__ WqB, short* __restrict__ WkB,
                                                    short* __restrict__ WvB, short* __restrict__ WoB) {
    int i = blockIdx.x * 256 + threadIdx.x;   // float4 index, 68608 total
    const float* src; short* dst; int off;
    if (i < 1024)      { src = Wq; dst = WqB; off = i; }
    else if (i < 2048) { src = Wk; dst = WkB; off = i - 1024; }
    else if (i < 3072) { src = Wv; dst = WvB; off = i - 2048; }
    else               { src = Wo; dst = WoB; off = i - 3072; }
    float4 t = reinterpret_cast<const float4*>(src)[off];
    uint2 d; d.x = pk2bf(t.x, t.y); d.y = pk2bf(t.z, t.w);
    reinterpret_cast<uint2*>(dst)[off] = d;
}

// ---------------------------------------------------------------------------
// Fused projections, one launch.
//  blocks [0,2048):    q  (transposed compute: A=Wq, B=X rows; packed stores)
//  blocks [2048,4096): k  (same)
//  blocks [4096,6144): v  (A=X, B=Wv; packed transposed stores -> vT[f][l])
// ---------------------------------------------------------------------------
__global__ __launch_bounds__(256) void proj_fused(const float* __restrict__ query, const float* __restrict__ key,
                                                  const float* __restrict__ value,
                                                  const short* __restrict__ WqB, const short* __restrict__ WkB,
                                                  const short* __restrict__ WvB,
                                                  short* __restrict__ Oq, short* __restrict__ Ok, short* __restrict__ OvT) {
    const int id = blockIdx.x;
    const int lane = threadIdx.x & 63;
    const int wave = threadIdx.x >> 6;
    const int quad = lane >> 4;
    const int c    = lane & 15;

    if (id < 4096) {
        const bool isq = id < 2048;
        const float* X = isq ? query : key;
        const short* W = isq ? WqB : WkB;
        short* O = isq ? Oq : Ok;
        const float oscale = isq ? QSCALE : 1.0f;
        const int xid = isq ? id : id - 2048;
        const long r0 = (long)xid * 64 + wave * 16;

        short8 xb[2];
#pragma unroll
        for (int kk = 0; kk < 2; ++kk) {
            const float* src = X + (r0 + c) * 64 + kk * 32 + quad * 8;
            xb[kk] = pack8(*reinterpret_cast<const float4*>(src), *reinterpret_cast<const float4*>(src + 4));
        }

        f32x4 acc[4];
#pragma unroll
        for (int ft = 0; ft < 4; ++ft) { acc[ft][0]=0.f; acc[ft][1]=0.f; acc[ft][2]=0.f; acc[ft][3]=0.f; }

#pragma unroll
        for (int ft = 0; ft < 4; ++ft)
#pragma unroll
            for (int kk = 0; kk < 2; ++kk) {
                short8 wa = *reinterpret_cast<const short8*>(W + (ft * 16 + c) * 64 + kk * 32 + quad * 8);
                acc[ft] = __builtin_amdgcn_mfma_f32_16x16x32_bf16(wa, xb[kk], acc[ft], 0, 0, 0);
            }

#pragma unroll
        for (int ft = 0; ft < 4; ++ft) {
            uint2 d;
            d.x = pk2bf(acc[ft][0] * oscale, acc[ft][1] * oscale);
            d.y = pk2bf(acc[ft][2] * oscale, acc[ft][3] * oscale);
            *reinterpret_cast<uint2*>(O + (r0 + c) * 64 + ft * 16 + quad * 4) = d;
        }
    } else {
        const int vid = id - 4096;
        const int bh = vid >> 5, lt = vid & 31;
        const int b = bh >> 3, h = bh & 7;
        const int l0 = lt * 64 + wave * 16;

        short8 xa[2];
#pragma unroll
        for (int kk = 0; kk < 2; ++kk) {
            const float* src = value + ((long)(b * LL + l0 + c) * EE + h * 64) + kk * 32 + quad * 8;
            xa[kk] = pack8(*reinterpret_cast<const float4*>(src), *reinterpret_cast<const float4*>(src + 4));
        }

        f32x4 acc[4];
#pragma unroll
        for (int nt = 0; nt < 4; ++nt) { acc[nt][0]=0.f; acc[nt][1]=0.f; acc[nt][2]=0.f; acc[nt][3]=0.f; }

#pragma unroll
        for (int nt = 0; nt < 4; ++nt)
#pragma unroll
            for (int kk = 0; kk < 2; ++kk) {
                short8 wb = *reinterpret_cast<const short8*>(WvB + (nt * 16 + c) * 64 + kk * 32 + quad * 8);
                acc[nt] = __builtin_amdgcn_mfma_f32_16x16x32_bf16(xa[kk], wb, acc[nt], 0, 0, 0);
            }

#pragma unroll
        for (int nt = 0; nt < 4; ++nt) {
            uint2 d;
            d.x = pk2bf(acc[nt][0], acc[nt][1]);
            d.y = pk2bf(acc[nt][2], acc[nt][3]);
            *reinterpret_cast<uint2*>(OvT + ((long)bh * 64 + nt * 16 + c) * LL + l0 + quad * 4) = d;
        }
    }
}

// ---------------------------------------------------------------------------
// Attention, no-max softmax. R3 per-wave structure (64 q-rows/wave, 256
// q-rows/block, 512 blocks, 2 waves/SIMD) + LDS DOUBLE-BUFFERED K/V tiles.
// R4/R5/R6 lessons: wave needs ~185 regs -> 2 waves/SIMD structural; register
// prefetch buffers spill (R6: WRITE 290MB scratch). Prefetch lives in LDS:
// the 4 waves share bh -> block-stages K(8KB)+V(8KB) per 64-key tile ONCE
// (4x less global traffic), waves read via conflict-free swizzled ds_read.
// Reg-staged copy (waves 0-1: K, waves 2-3: V; 4x dwordx4 each) issued
// BEFORE the tile's compute -> HBM/L2 latency hides under ~2k cy of MFMA.
// XOR swizzle addr^=((row&7)<<4) on BOTH ds_write and ds_read (rule #21):
// raw 128B-row tiles are a 32-way bank conflict on ds_read_b128.
// S^T = K Q^T  (C: col=q (lane&31), row=key (reg&3)+8*(reg>>2)+4*hl)
// P^T B-fragments IN-REGISTER via v_permlane32_swap_b32 (verified R3):
//   rA = swap(xd[even][d], xd[odd][d]); pb.u[d]=rA[0]; pb.u[2+d]=rA[1].
// O^T = V^T P^T, accumulated in f32x16; epilogue scales by 1/l.
// ---------------------------------------------------------------------------
#define TILE(kf, vfr) { \
    _Pragma("unroll") for (int t = 0; t < 2; ++t) \
    _Pragma("unroll") for (int kt = 0; kt < 2; ++kt) { \
        f32x16 s; \
        _Pragma("unroll") for (int i = 0; i < 16; ++i) s[i] = 0.f; \
        _Pragma("unroll") for (int ks = 0; ks < 4; ++ks) \
            s = __builtin_amdgcn_mfma_f32_32x32x16_bf16(kf[kt][ks], aq[t][ks], s, 0, 0, 0); \
        uint32_t xd[4][2]; float lac = 0.f; \
        _Pragma("unroll") for (int g = 0; g < 4; ++g) { \
            const float p0 = __builtin_amdgcn_exp2f(s[4 * g + 0]); \
            const float p1 = __builtin_amdgcn_exp2f(s[4 * g + 1]); \
            const float p2 = __builtin_amdgcn_exp2f(s[4 * g + 2]); \
            const float p3 = __builtin_amdgcn_exp2f(s[4 * g + 3]); \
            lac += (p0 + p1) + (p2 + p3); \
            xd[g][0] = pk2bf(p0, p1); xd[g][1] = pk2bf(p2, p3); \
        } \
        l[t] += lac; \
        _Pragma("unroll") for (int kt2 = 0; kt2 < 2; ++kt2) { \
            u32x2v rA = __builtin_amdgcn_permlane32_swap(xd[2 * kt2][0], xd[2 * kt2 + 1][0], false, false); \
            u32x2v rB = __builtin_amdgcn_permlane32_swap(xd[2 * kt2][1], xd[2 * kt2 + 1][1], false, false); \
            union { uint32_t u[4]; short8 s8; } pb; \
            pb.u[0] = rA[0]; pb.u[1] = rB[0]; pb.u[2] = rA[1]; pb.u[3] = rB[1]; \
            const int kk = kt * 2 + kt2; \
            of[t][0] = __builtin_amdgcn_mfma_f32_32x32x16_bf16(vfr[0][kk], pb.s8, of[t][0], 0, 0, 0); \
            of[t][1] = __builtin_amdgcn_mfma_f32_32x32x16_bf16(vfr[1][kk], pb.s8, of[t][1], 0, 0, 0); \
        } \
    } }

__global__ __launch_bounds__(256, 2) void attn_kernel(const short* __restrict__ Q, const short* __restrict__ K,
                                                      const short* __restrict__ VT, short* __restrict__ Oattn) {
    __shared__ __align__(16) char smem[2][16384];   // [dbuf][K 8KB | V 8KB]
    const int lane = threadIdx.x & 63;
    const int wave = threadIdx.x >> 6;
    const int hl = lane >> 5;          // lane half (bit 5)
    const int c  = lane & 31;          // col within 32 (q-index / A-row)
    const int bh = blockIdx.x & 63;    // blocks sharing bh are 64 apart -> same XCD
    const int qs = blockIdx.x >> 6;    // 0..7
    const int b = bh >> 3, head = bh & 7;
    const int q0 = qs * 256 + wave * 64;

    const short* Kb = K  + (long)bh * LL * 64;
    const short* Vb = VT + (long)bh * 64 * LL;

    // ---- staging geometry (reg-staged, swizzled ds_write) ----
    // linear dest byte x = wave*4096 + j*1024 + lane*16 over 16KB tile
    // (x<8192: K rows kb..kb+63 x 128B; x>=8192: V feats 0..63 x 128B).
    // LDS write addr = x ^ (((x>>7)&7)<<4); (x>>7)&7 == (lane>>3)&7.
    const int wr = wave * 4096 + ((lane * 16) ^ (((lane >> 3) & 7) << 4));
    const char* sbase;  // byte addr of (j=0, kb=0) source for this lane
    long sstep, kbmul;  // per-j stride, per-key-index stride (bytes)
    if (wave < 2) {
        sbase = (const char*)Kb + wave * 4096 + lane * 16;
        sstep = 1024; kbmul = 128;
    } else {
        sbase = (const char*)Vb + ((long)((wave - 2) * 32 + (lane >> 3))) * 4096 + (lane & 7) * 16;
        sstep = 8 * 4096; kbmul = 2;
    }

    // ---- swizzled ds_read offsets ----
    const int swzl = (c & 7) << 4;

    // Q B-fragments (S^T B-operand): B[k=feat][col=q]; k = ks*16 + hl*8 + j
    short8 aq[2][4];
#pragma unroll
    for (int t = 0; t < 2; ++t)
#pragma unroll
        for (int ks = 0; ks < 4; ++ks)
            aq[t][ks] = *reinterpret_cast<const short8*>(Q + ((long)bh * LL + q0 + t * 32 + c) * 64 + ks * 16 + hl * 8);

    f32x16 of[2][2];
#pragma unroll
    for (int t = 0; t < 2; ++t)
#pragma unroll
        for (int ft = 0; ft < 2; ++ft)
#pragma unroll
            for (int i = 0; i < 16; ++i) of[t][ft][i] = 0.f;
    float l[2] = {0.f, 0.f};

    // prologue: stage tile 0 into buf 0
    {
        uint4 st[4];
#pragma unroll
        for (int j = 0; j < 4; ++j) st[j] = *reinterpret_cast<const uint4*>(sbase + j * sstep);
#pragma unroll
        for (int j = 0; j < 4; ++j) *reinterpret_cast<uint4*>(&smem[0][wr + j * 1024]) = st[j];
    }
    __syncthreads();

    int cur = 0;
#pragma unroll 1
    for (int kb = 0; kb < LL; kb += 64) {
        // issue next tile's stage loads first (fly under this tile's compute)
        uint4 st[4];
        const long nkb = (kb + 64) & (LL - 1);   // wrap: dummy restage of tile 0 on last iter
#pragma unroll
        for (int j = 0; j < 4; ++j) st[j] = *reinterpret_cast<const uint4*>(sbase + j * sstep + nkb * kbmul);

        // compute tile kb from smem[cur]
        short8 kf[2][4], vf[2][4];
        {
            const char* bp = &smem[cur][0];
#pragma unroll
            for (int kt_ = 0; kt_ < 2; ++kt_)
#pragma unroll
                for (int ks_ = 0; ks_ < 4; ++ks_)
                    kf[kt_][ks_] = *reinterpret_cast<const short8*>(bp + (kt_ * 32 + c) * 128 + ((ks_ * 32 + hl * 16) ^ swzl));
#pragma unroll
            for (int ft_ = 0; ft_ < 2; ++ft_)
#pragma unroll
                for (int kk_ = 0; kk_ < 4; ++kk_)
                    vf[ft_][kk_] = *reinterpret_cast<const short8*>(bp + 8192 + (ft_ * 32 + c) * 128 + ((kk_ * 32 + hl * 16) ^ swzl));
        }
        TILE(kf, vf);

        // write staged tile -> smem[cur^1] (WAR-safe: prev reads of cur^1
        // completed before last barrier), then barrier publishes it
#pragma unroll
        for (int j = 0; j < 4; ++j) *reinterpret_cast<uint4*>(&smem[cur ^ 1][wr + j * 1024]) = st[j];
        __syncthreads();
        cur ^= 1;
    }

    // denom: lane holds partial over its half's keys; one swap finishes it
    float inv[2];
#pragma unroll
    for (int t = 0; t < 2; ++t) {
        l[t] += __shfl_xor(l[t], 32);
        inv[t] = 1.0f / l[t];
    }

    // epilogue: of[t][ft] C-layout: col=c (q), row = 8g + 4hl + r (feat within 32)
#pragma unroll
    for (int t = 0; t < 2; ++t) {
        const long row = (long)b * LL + q0 + t * 32 + c;
#pragma unroll
        for (int ft = 0; ft < 2; ++ft)
#pragma unroll
            for (int g = 0; g < 4; ++g) {
                const float v0 = of[t][ft][4 * g + 0] * inv[t], v1 = of[t][ft][4 * g + 1] * inv[t];
                const float v2 = of[t][ft][4 * g + 2] * inv[t], v3 = of[t][ft][4 * g + 3] * inv[t];
                uint2 d; d.x = pk2bf(v0, v1); d.y = pk2bf(v2, v3);
                *reinterpret_cast<uint2*>(Oattn + row * EE + head * 64 + ft * 32 + g * 8 + hl * 4) = d;
            }
    }
}

// ---------------------------------------------------------------------------
// out^T-compute = Wo . attn^T: lane holds 4 consecutive out-features -> float4
// ---------------------------------------------------------------------------
__global__ __launch_bounds__(256) void out_proj(const short* __restrict__ A, const short* __restrict__ WoB,
                                                const float* __restrict__ bo, float* __restrict__ out) {
    const int lane = threadIdx.x & 63;
    const int wave = threadIdx.x >> 6;
    const int quad = lane >> 4;
    const int c    = lane & 15;
    const int nb = blockIdx.x;   // 0..7 feature block
    const int rb = blockIdx.y;   // 0..255
    const long r0 = (long)rb * 64 + wave * 16;

    f32x4 acc[4];
#pragma unroll
    for (int ft = 0; ft < 4; ++ft) { acc[ft][0]=0.f; acc[ft][1]=0.f; acc[ft][2]=0.f; acc[ft][3]=0.f; }

    for (int ks = 0; ks < 16; ++ks) {
        short8 bfr = *reinterpret_cast<const short8*>(A + (r0 + c) * EE + ks * 32 + quad * 8);
#pragma unroll
        for (int ft = 0; ft < 4; ++ft) {
            short8 afr = *reinterpret_cast<const short8*>(WoB + ((long)(nb * 64 + ft * 16 + c)) * EE + ks * 32 + quad * 8);
            acc[ft] = __builtin_amdgcn_mfma_f32_16x16x32_bf16(afr, bfr, acc[ft], 0, 0, 0);
        }
    }

#pragma unroll
    for (int ft = 0; ft < 4; ++ft) {
        float4 bias = *reinterpret_cast<const float4*>(bo + nb * 64 + ft * 16 + quad * 4);
        float4 res;
        res.x = acc[ft][0] + bias.x; res.y = acc[ft][1] + bias.y;
        res.z = acc[ft][2] + bias.z; res.w = acc[ft][3] + bias.w;
        *reinterpret_cast<float4*>(out + (r0 + c) * EE + nb * 64 + ft * 16 + quad * 4) = res;
    }
}

extern "C" void kernel_launch(void* const* d_in, const int* in_sizes, int n_in,
                              void* d_out, int out_size, void* d_ws, size_t ws_size,
                              hipStream_t stream) {
    const float* query = (const float*)d_in[0];
    const float* key   = (const float*)d_in[1];
    const float* value = (const float*)d_in[2];
    const float* Wq    = (const float*)d_in[3];
    const float* Wk    = (const float*)d_in[4];
    const float* Wv    = (const float*)d_in[5];
    const float* Wo    = (const float*)d_in[6];
    const float* bo    = (const float*)d_in[7];
    float* out = (float*)d_out;

    char* ws = (char*)d_ws;
    const size_t SZ = 16777216;             // B*H*L*64 bf16 bytes
    short* q_ws    = (short*)(ws);
    short* k_ws    = (short*)(ws + SZ);
    short* vT_ws   = (short*)(ws + 2 * SZ);
    short* attn_ws = (short*)(ws + 3 * SZ);
    short* wo_ws   = (short*)(ws + 4 * SZ);            // 512 KiB
    short* wq_ws   = (short*)(ws + 4 * SZ + 524288);   // 8 KiB each
    short* wk_ws   = (short*)(ws + 4 * SZ + 532480);
    short* wv_ws   = (short*)(ws + 4 * SZ + 540672);

    prep_weights<<<268, 256, 0, stream>>>(Wq, Wk, Wv, Wo, wq_ws, wk_ws, wv_ws, wo_ws);
    proj_fused<<<6144, 256, 0, stream>>>(query, key, value, wq_ws, wk_ws, wv_ws, q_ws, k_ws, vT_ws);
    attn_kernel<<<512, 256, 0, stream>>>(q_ws, k_ws, vT_ws, attn_ws);
    out_proj<<<dim3(8, 256), 256, 0, stream>>>(attn_ws, wo_ws, bo, out);
}